// Round 3
// baseline (5674.875 us; speedup 1.0000x reference)
//
#include <hip/hip_runtime.h>
#include <hip/hip_bf16.h>

typedef unsigned short u16;
typedef unsigned int u32;
typedef __attribute__((ext_vector_type(8))) short short8;
typedef __attribute__((ext_vector_type(4))) float f32x4;

static constexpr int NB = 256;    // batch
static constexpr int NN = 2048;   // hidden n
static constexpr int KK = 2048;   // contraction dim
static constexpr int DD = 512;    // input features
static constexpr float ALPHA = 0.1f;
static constexpr int NITER = 128;   // fixed count: observed iters-to-1e-4 is 75-80 (r1:73, r2:79)
static constexpr int CHUNK = 256;   // k per LDS chunk
static constexpr int NCHUNK = KK / CHUNK;

__device__ __forceinline__ float bf2f(u16 u) {
  union { unsigned int i; float f; } v; v.i = ((unsigned int)u) << 16; return v.f;
}
__device__ __forceinline__ u16 f2bf(float f) {  // RNE bf16
  union { float f; unsigned int i; } v; v.f = f;
  unsigned int x = v.i;
  return (u16)((x + 0x7fffu + ((x >> 16) & 1u)) >> 16);
}

// ---------------- K1: Aht[i][k] = bf16(A[k][i]), Alt = residual ----------------
__global__ __launch_bounds__(256) void k_transpose_split(
    const float* __restrict__ A, u16* __restrict__ Aht, u16* __restrict__ Alt) {
  __shared__ float tile[64][65];
  int bx = blockIdx.x & 31;   // i-tile
  int by = blockIdx.x >> 5;   // k-tile
  int i0 = bx << 6, k0 = by << 6;
  int c = threadIdx.x & 63, r4 = threadIdx.x >> 6;
  for (int rr = r4; rr < 64; rr += 4)
    tile[rr][c] = A[(size_t)(k0 + rr) * NN + i0 + c];
  __syncthreads();
  for (int rr = r4; rr < 64; rr += 4) {
    float v = tile[c][rr];                       // = A[k0+c][i0+rr]
    size_t o = (size_t)(i0 + rr) * KK + k0 + c;  // Aht[i][k]
    u16 hv = f2bf(v);
    Aht[o] = hv;
    Alt[o] = f2bf(v - bf2f(hv));
  }
}

// ------ K2: T = (1 - a*m) I + a*(S - S^T - A^T A), stored row-major bf16 split ------
__global__ __launch_bounds__(512) void k_build_T(
    const u16* __restrict__ Aht, const u16* __restrict__ Alt,
    const float* __restrict__ S, const float* __restrict__ mraw,
    u16* __restrict__ Th, u16* __restrict__ Tl) {
  int bid = blockIdx.x;            // 256 blocks, output tile 128x128
  int it0 = (bid >> 4) << 7;
  int jt0 = (bid & 15) << 7;
  int lane = threadIdx.x & 63, wid = threadIdx.x >> 6;
  int wm = wid >> 2, wn = wid & 3; // 2x4 waves, wave tile 64x32
  int ib = it0 + wm * 64;
  int jb = jt0 + wn * 32;
  int lcol = lane & 15, kg = lane >> 4;
  f32x4 acc[4][2] = {};
  size_t ar[4], br[2];
#pragma unroll
  for (int mf = 0; mf < 4; ++mf) ar[mf] = (size_t)(ib + mf * 16 + lcol) * KK + kg * 8;
#pragma unroll
  for (int nf = 0; nf < 2; ++nf) br[nf] = (size_t)(jb + nf * 16 + lcol) * KK + kg * 8;
  for (int kk = 0; kk < KK; kk += 32) {
    short8 ah[4], al[4], bh[2], bl[2];
#pragma unroll
    for (int mf = 0; mf < 4; ++mf) {
      ah[mf] = *(const short8*)(Aht + ar[mf] + kk);
      al[mf] = *(const short8*)(Alt + ar[mf] + kk);
    }
#pragma unroll
    for (int nf = 0; nf < 2; ++nf) {
      bh[nf] = *(const short8*)(Aht + br[nf] + kk);
      bl[nf] = *(const short8*)(Alt + br[nf] + kk);
    }
#pragma unroll
    for (int mf = 0; mf < 4; ++mf)
#pragma unroll
      for (int nf = 0; nf < 2; ++nf) {
        acc[mf][nf] = __builtin_amdgcn_mfma_f32_16x16x32_bf16(ah[mf], bh[nf], acc[mf][nf], 0, 0, 0);
        acc[mf][nf] = __builtin_amdgcn_mfma_f32_16x16x32_bf16(al[mf], bh[nf], acc[mf][nf], 0, 0, 0);
        acc[mf][nf] = __builtin_amdgcn_mfma_f32_16x16x32_bf16(ah[mf], bl[nf], acc[mf][nf], 0, 0, 0);
      }
  }
  float m = log1pf(expf(mraw[0]));   // softplus
  float dg = 1.0f - ALPHA * m;
#pragma unroll
  for (int mf = 0; mf < 4; ++mf)
#pragma unroll
    for (int nf = 0; nf < 2; ++nf)
#pragma unroll
      for (int e = 0; e < 4; ++e) {
        int i = ib + mf * 16 + kg * 4 + e;   // D row = (lane>>4)*4+e  [m89-verified]
        int j = jb + nf * 16 + lcol;         // D col = lane&15
        float tv = ALPHA * (S[(size_t)i * NN + j] - S[(size_t)j * NN + i] - acc[mf][nf][e]);
        if (i == j) tv += dg;
        size_t o = (size_t)i * KK + j;
        u16 hv = f2bf(tv);
        Th[o] = hv;
        Tl[o] = f2bf(tv - bf2f(hv));
      }
}

// ---------------- K3: cp[b][n] = a*(U[n,:]·x[b,:] + bias[n]) ----------------
__global__ __launch_bounds__(256) void k_build_c(
    const float* __restrict__ U, const float* __restrict__ bias,
    const float* __restrict__ x, float* __restrict__ cp) {
  int b = blockIdx.x >> 3;
  int n = ((blockIdx.x & 7) << 8) + threadIdx.x;
  const float4* xr = (const float4*)(x + (size_t)b * DD);
  const float4* ur = (const float4*)(U + (size_t)n * DD);
  float acc = 0.f;
  for (int d = 0; d < DD / 4; ++d) {
    float4 xv = xr[d], uv = ur[d];
    acc += xv.x * uv.x + xv.y * uv.y + xv.z * uv.z + xv.w * uv.w;
  }
  cp[(size_t)b * NN + n] = ALPHA * (acc + bias[n]);
}

// ---------------- K4: fixed-point iteration, zero fences ----------------
// z packed: zp[b][n] = bf16_hi | bf16_lo<<16, ALL accesses system-scope atomics
// (sc0 sc1: bypass L1/L2, coherent at L3). T/cp plain cached -> L2 stays warm.
// Fixed NITER; barrier = one relaxed atomic counter + sleep-spin (tid 0 only).
// A-panel (z rows) LDS-staged in K-chunks, double-buffered, XOR-16B swizzled.
__global__ __launch_bounds__(512) void k_iterate(
    const u16* __restrict__ Th, const u16* __restrict__ Tl,
    const float* __restrict__ cp, u32* zp,
    u32* ctr, float* __restrict__ out) {
  int bid = blockIdx.x;
  // XCD swizzle: blocks bid%8==x handle n-panels [256x,256x+256) -> XCD-local T slice
  int xcd = bid & 7, g = bid >> 3;
  int ntile = xcd * 4 + (g & 3);   // 0..31
  int btile = g >> 2;              // 0..7
  int b0 = btile * 32, n0 = ntile * 64;
  int tid = threadIdx.x, lane = tid & 63, wid = tid >> 6;
  int wm = wid >> 2, wn = wid & 3;   // 2x4 waves of 16x16
  int lcol = lane & 15, kg = lane >> 4;
  int wn0 = n0 + wn * 16;
  const u16* pBh = Th + (size_t)(wn0 + lcol) * KK + kg * 8;
  const u16* pBl = Tl + (size_t)(wn0 + lcol) * KK + kg * 8;
  int arow = wm * 16 + lcol;        // block-local z row this lane's A-frag reads
  int swz = (lcol & 7) << 4;        // XOR-16B swizzle (arow&7 == lcol&7)
  int eb = b0 + wm * 16 + kg * 4;   // 4 output batch rows owned by this thread
  int en = wn0 + lcol;              // output n column owned by this thread

  // staging assignment: thread stages u32 idx = tid + i*512 of the 32x256 chunk
  int srbase = tid >> 8;            // 0 or 1 (row = srbase + 2*i)
  int sc = tid & 255;               // col within chunk
  int sbyte = (sc << 1) ^ 0;        // swizzle applied per-row below

  __shared__ u16 lds[2][2][32][CHUNK];   // [buf][h/l][row][k] 64 KiB

  float zreg[4], creg[4];
#pragma unroll
  for (int e = 0; e < 4; ++e) {
    zreg[e] = 0.f;
    creg[e] = cp[(size_t)(eb + e) * NN + en];
  }

  for (int it = 0; it < NITER; ++it) {
    f32x4 a0 = {0.f, 0.f, 0.f, 0.f};
    f32x4 a1 = {0.f, 0.f, 0.f, 0.f};
    f32x4 a2 = {0.f, 0.f, 0.f, 0.f};
    if (it > 0) {
      // prologue: stage chunk 0 into buf 0
      {
        u32 v[16];
#pragma unroll
        for (int i = 0; i < 16; ++i)
          v[i] = __hip_atomic_load(zp + (size_t)(b0 + srbase + 2 * i) * NN + sc,
                                   __ATOMIC_RELAXED, __HIP_MEMORY_SCOPE_SYSTEM);
#pragma unroll
        for (int i = 0; i < 16; ++i) {
          int r = srbase + 2 * i;
          int bo = (sc << 1) ^ ((r & 7) << 4);
          *(u16*)((char*)&lds[0][0][r][0] + bo) = (u16)(v[i] & 0xffffu);
          *(u16*)((char*)&lds[0][1][r][0] + bo) = (u16)(v[i] >> 16);
        }
      }
      __syncthreads();
      for (int ch = 0; ch < NCHUNK; ++ch) {
        int bf = ch & 1;
        u32 nv[16];
        if (ch + 1 < NCHUNK) {   // issue next-chunk loads early (latency under MFMA)
#pragma unroll
          for (int i = 0; i < 16; ++i)
            nv[i] = __hip_atomic_load(
                zp + (size_t)(b0 + srbase + 2 * i) * NN + (ch + 1) * CHUNK + sc,
                __ATOMIC_RELAXED, __HIP_MEMORY_SCOPE_SYSTEM);
        }
        const u16* bh = pBh + ch * CHUNK;
        const u16* bl = pBl + ch * CHUNK;
        const char* ah = (const char*)&lds[bf][0][arow][0];
        const char* al = (const char*)&lds[bf][1][arow][0];
#pragma unroll
        for (int ks = 0; ks < CHUNK / 32; ++ks) {
          short8 bvh = *(const short8*)(bh + ks * 32);
          short8 bvl = *(const short8*)(bl + ks * 32);
          int ab = (ks * 64 + kg * 16) ^ swz;
          short8 avh = *(const short8*)(ah + ab);
          short8 avl = *(const short8*)(al + ab);
          a0 = __builtin_amdgcn_mfma_f32_16x16x32_bf16(avh, bvh, a0, 0, 0, 0);
          a1 = __builtin_amdgcn_mfma_f32_16x16x32_bf16(avl, bvh, a1, 0, 0, 0);
          a2 = __builtin_amdgcn_mfma_f32_16x16x32_bf16(avh, bvl, a2, 0, 0, 0);
        }
        if (ch + 1 < NCHUNK) {   // write-late: ds_write after compute (T14)
#pragma unroll
          for (int i = 0; i < 16; ++i) {
            int r = srbase + 2 * i;
            int bo = (sc << 1) ^ ((r & 7) << 4);
            *(u16*)((char*)&lds[bf ^ 1][0][r][0] + bo) = (u16)(nv[i] & 0xffffu);
            *(u16*)((char*)&lds[bf ^ 1][1][r][0] + bo) = (u16)(nv[i] >> 16);
          }
        }
        __syncthreads();
      }
    }
    // epilogue: z' = relu(T z + c); store packed bf16 split, write-through
#pragma unroll
    for (int e = 0; e < 4; ++e) {
      float p = a0[e] + a1[e] + a2[e] + creg[e];
      float zn = fmaxf(p, 0.f);
      zreg[e] = zn;
      u16 hv = f2bf(zn);
      u16 lv = f2bf(zn - bf2f(hv));
      __hip_atomic_store(zp + (size_t)(eb + e) * NN + en,
                         (u32)hv | ((u32)lv << 16),
                         __ATOMIC_RELAXED, __HIP_MEMORY_SCOPE_SYSTEM);
    }
    asm volatile("s_waitcnt vmcnt(0)" ::: "memory");  // stores at coherent point
    __syncthreads();
    if (tid == 0) {
      __hip_atomic_fetch_add(ctr, 1u, __ATOMIC_RELAXED, __HIP_MEMORY_SCOPE_SYSTEM);
      u32 tgt = 256u * (u32)(it + 1);
      while (__hip_atomic_load(ctr, __ATOMIC_RELAXED, __HIP_MEMORY_SCOPE_SYSTEM) < tgt)
        __builtin_amdgcn_s_sleep(1);
    }
    __syncthreads();
  }

  // final write: out[n*NB + b], 4 consecutive b per thread -> one float4
  *(float4*)(out + (size_t)en * NB + eb) = make_float4(zreg[0], zreg[1], zreg[2], zreg[3]);
  (void)sbyte;
}

extern "C" void kernel_launch(void* const* d_in, const int* in_sizes, int n_in,
                              void* d_out, int out_size, void* d_ws, size_t ws_size,
                              hipStream_t stream) {
  const float* A    = (const float*)d_in[0];
  const float* S    = (const float*)d_in[1];
  const float* mraw = (const float*)d_in[2];
  const float* U    = (const float*)d_in[3];
  const float* bias = (const float*)d_in[4];
  const float* x    = (const float*)d_in[5];
  float* out = (float*)d_out;

  char* base = (char*)d_ws;
  const size_t ASZ = (size_t)NN * KK * 2;  // 8 MiB per bf16 matrix
  u16* Aht = (u16*)(base);                 // dead after k_build_T
  u16* Alt = (u16*)(base + ASZ);           // dead after k_build_T
  u16* Thp = (u16*)(base + 2 * ASZ);
  u16* Tlp = (u16*)(base + 3 * ASZ);
  // iteration state aliases the dead Aht region (only written after build kernels):
  float* cpp  = (float*)(base);                        // 2 MiB
  u32*   zpp  = (u32*)(base + 2u * 1024 * 1024);       // 2 MiB packed z
  u32*   ctrp = (u32*)(base + 5u * 1024 * 1024);       // barrier counter (dead zone)

  k_transpose_split<<<dim3(1024), dim3(256), 0, stream>>>(A, Aht, Alt);
  k_build_T<<<dim3(256), dim3(512), 0, stream>>>(Aht, Alt, S, mraw, Thp, Tlp);
  k_build_c<<<dim3(2048), dim3(256), 0, stream>>>(U, bias, x, cpp);
  hipMemsetAsync(ctrp, 0, sizeof(u32), stream);  // AFTER builders (they trash this region)

  void* kargs[] = { (void*)&Thp, (void*)&Tlp, (void*)&cpp,
                    (void*)&zpp, (void*)&ctrp, (void*)&out };
  hipLaunchCooperativeKernel((const void*)k_iterate, dim3(256), dim3(512),
                             kargs, 0, stream);
}

// Round 5
// 3353.262 us; speedup vs baseline: 1.6923x; 1.6923x over previous
//
#include <hip/hip_runtime.h>
#include <hip/hip_bf16.h>

typedef unsigned short u16;
typedef unsigned int u32;
typedef __attribute__((ext_vector_type(8))) short short8;
typedef __attribute__((ext_vector_type(4))) float f32x4;
typedef __attribute__((ext_vector_type(4))) unsigned int u32x4;

static constexpr int NB = 256;    // batch
static constexpr int NN = 2048;   // hidden n
static constexpr int KK = 2048;   // contraction dim
static constexpr int DD = 512;    // input features
static constexpr float ALPHA = 0.1f;
static constexpr int NITER = 150; // sync iters-to-tol ~79 (r1/r2); 150 covers async staleness

__device__ __forceinline__ float bf2f(u16 u) {
  union { unsigned int i; float f; } v; v.i = ((unsigned int)u) << 16; return v.f;
}
__device__ __forceinline__ u16 f2bf(float f) {  // RNE bf16
  union { float f; unsigned int i; } v; v.f = f;
  unsigned int x = v.i;
  return (u16)((x + 0x7fffu + ((x >> 16) & 1u)) >> 16);
}
__device__ __forceinline__ u32 packsplit(float z) {
  u16 hv = f2bf(z);
  u16 lv = f2bf(z - bf2f(hv));
  return (u32)hv | ((u32)lv << 16);
}

// ---------------- K1: Aht[i][k] = bf16(A[k][i]), Alt = residual ----------------
__global__ __launch_bounds__(256) void k_transpose_split(
    const float* __restrict__ A, u16* __restrict__ Aht, u16* __restrict__ Alt) {
  __shared__ float tile[64][65];
  int bx = blockIdx.x & 31;   // i-tile
  int by = blockIdx.x >> 5;   // k-tile
  int i0 = bx << 6, k0 = by << 6;
  int c = threadIdx.x & 63, r4 = threadIdx.x >> 6;
  for (int rr = r4; rr < 64; rr += 4)
    tile[rr][c] = A[(size_t)(k0 + rr) * NN + i0 + c];
  __syncthreads();
  for (int rr = r4; rr < 64; rr += 4) {
    float v = tile[c][rr];                       // = A[k0+c][i0+rr]
    size_t o = (size_t)(i0 + rr) * KK + k0 + c;  // Aht[i][k]
    u16 hv = f2bf(v);
    Aht[o] = hv;
    Alt[o] = f2bf(v - bf2f(hv));
  }
}

// --- K2: T = (1-a*m)I + a*(S - S^T - A^T A); off-diag -> bf16 Tob (diag zeroed),
//     exact fp32 diagonal -> Tdiag[n]. Split-bf16 3-MFMA for G = A^T A. ---
__global__ __launch_bounds__(512) void k_build_T(
    const u16* __restrict__ Aht, const u16* __restrict__ Alt,
    const float* __restrict__ S, const float* __restrict__ mraw,
    u16* __restrict__ Tob, float* __restrict__ Tdiag) {
  int bid = blockIdx.x;            // 256 blocks, output tile 128x128
  int it0 = (bid >> 4) << 7;
  int jt0 = (bid & 15) << 7;
  int lane = threadIdx.x & 63, wid = threadIdx.x >> 6;
  int wm = wid >> 2, wn = wid & 3; // 2x4 waves, wave tile 64x32
  int ib = it0 + wm * 64;
  int jb = jt0 + wn * 32;
  int lcol = lane & 15, kg = lane >> 4;
  f32x4 acc[4][2] = {};
  size_t ar[4], br[2];
#pragma unroll
  for (int mf = 0; mf < 4; ++mf) ar[mf] = (size_t)(ib + mf * 16 + lcol) * KK + kg * 8;
#pragma unroll
  for (int nf = 0; nf < 2; ++nf) br[nf] = (size_t)(jb + nf * 16 + lcol) * KK + kg * 8;
  for (int kk = 0; kk < KK; kk += 32) {
    short8 ah[4], al[4], bh[2], bl[2];
#pragma unroll
    for (int mf = 0; mf < 4; ++mf) {
      ah[mf] = *(const short8*)(Aht + ar[mf] + kk);
      al[mf] = *(const short8*)(Alt + ar[mf] + kk);
    }
#pragma unroll
    for (int nf = 0; nf < 2; ++nf) {
      bh[nf] = *(const short8*)(Aht + br[nf] + kk);
      bl[nf] = *(const short8*)(Alt + br[nf] + kk);
    }
#pragma unroll
    for (int mf = 0; mf < 4; ++mf)
#pragma unroll
      for (int nf = 0; nf < 2; ++nf) {
        acc[mf][nf] = __builtin_amdgcn_mfma_f32_16x16x32_bf16(ah[mf], bh[nf], acc[mf][nf], 0, 0, 0);
        acc[mf][nf] = __builtin_amdgcn_mfma_f32_16x16x32_bf16(al[mf], bh[nf], acc[mf][nf], 0, 0, 0);
        acc[mf][nf] = __builtin_amdgcn_mfma_f32_16x16x32_bf16(ah[mf], bl[nf], acc[mf][nf], 0, 0, 0);
      }
  }
  float m = log1pf(expf(mraw[0]));   // softplus
  float dg = 1.0f - ALPHA * m;
#pragma unroll
  for (int mf = 0; mf < 4; ++mf)
#pragma unroll
    for (int nf = 0; nf < 2; ++nf)
#pragma unroll
      for (int e = 0; e < 4; ++e) {
        int i = ib + mf * 16 + kg * 4 + e;   // D row = (lane>>4)*4+e  [m89-verified]
        int j = jb + nf * 16 + lcol;         // D col = lane&15
        float tv = ALPHA * (S[(size_t)i * NN + j] - S[(size_t)j * NN + i] - acc[mf][nf][e]);
        size_t o = (size_t)i * KK + j;
        if (i == j) {
          Tdiag[i] = tv + dg;   // exact fp32 diagonal
          Tob[o] = 0;
        } else {
          Tob[o] = f2bf(tv);
        }
      }
}

// ---------------- K3: cp[b][n] = a*(U[n,:]·x[b,:] + bias[n]) ----------------
__global__ __launch_bounds__(256) void k_build_c(
    const float* __restrict__ U, const float* __restrict__ bias,
    const float* __restrict__ x, float* __restrict__ cp) {
  int b = blockIdx.x >> 3;
  int n = ((blockIdx.x & 7) << 8) + threadIdx.x;
  const float4* xr = (const float4*)(x + (size_t)b * DD);
  const float4* ur = (const float4*)(U + (size_t)n * DD);
  float acc = 0.f;
  for (int d = 0; d < DD / 4; ++d) {
    float4 xv = xr[d], uv = ur[d];
    acc += xv.x * uv.x + xv.y * uv.y + xv.z * uv.z + xv.w * uv.w;
  }
  cp[(size_t)b * NN + n] = ALPHA * (acc + bias[n]);
}

// ---------------- K4: ASYNC fixed-point iteration (no barrier, no fences) ----------
// Block = 16 batch rows x 128 n cols; 8 waves each own a 256-wide K-slice and compute
// partial sums for the whole 16x128 tile; cross-wave reduce via 64KB LDS exchange.
// z packed bf16(hi|lo) u32, accessed with sc0 sc1 (L3-coherent) wide asm loads/stores.
// T_off single bf16 (L2-resident per-XCD slice); exact diagonal applied in registers.
#define ALD(dst, OFF) \
  asm volatile("global_load_dwordx4 %0, %1, off offset:" OFF " sc0 sc1" \
               : "=v"(dst) : "v"(pa))

__global__ __launch_bounds__(512) void k_iterate(
    const u16* __restrict__ Tob, const float* __restrict__ Tdiag,
    const float* __restrict__ cp, u32* zp, float* __restrict__ out) {
  int bid = blockIdx.x;
  int xcd = bid & 7, g = bid >> 3;
  int ntile = xcd * 2 + (g & 1);   // 0..15: XCD-local 1MB T_off slice (perf heuristic only)
  int btile = g >> 1;              // 0..15
  int b0 = btile * 16, n0 = ntile * 128;
  int tid = threadIdx.x, lane = tid & 63, w = tid >> 6;
  int lcol = lane & 15, kg = lane >> 4;
  int kbase = w * 256;             // this wave's K-slice

  const u32* pa = zp + (size_t)(b0 + lcol) * NN + kbase + kg * 8;       // A rows (z)
  const u16* pB = Tob + (size_t)(n0 + lcol) * KK + kbase + kg * 8;      // B rows (T_off)

  // epilogue ownership: thread owns (b0+ob, n0+on .. +3) FOREVER
  int ob = tid >> 5;           // 0..15
  int on = (tid & 31) * 4;     // 0..124
  const float4 cv = *(const float4*)(cp + (size_t)(b0 + ob) * NN + n0 + on);
  const float4 dv = *(const float4*)(Tdiag + n0 + on);
  u32* pz = zp + (size_t)(b0 + ob) * NN + n0 + on;
  float zold0 = 0.f, zold1 = 0.f, zold2 = 0.f, zold3 = 0.f;

  __shared__ float part[8 * 16 * 128];   // [wave][b][n^swz] 64 KiB

#pragma unroll 1
  for (int it = 0; it < NITER; ++it) {
    // ---- A phase: 16 wide syscope loads (64B/lane contiguous), one drain ----
    u32x4 q0,q1,q2,q3,q4,q5,q6,q7,q8,q9,q10,q11,q12,q13,q14,q15;
    ALD(q0,"0");    ALD(q1,"16");   ALD(q2,"128");  ALD(q3,"144");
    ALD(q4,"256");  ALD(q5,"272");  ALD(q6,"384");  ALD(q7,"400");
    ALD(q8,"512");  ALD(q9,"528");  ALD(q10,"640"); ALD(q11,"656");
    ALD(q12,"768"); ALD(q13,"784"); ALD(q14,"896"); ALD(q15,"912");
    asm volatile("s_waitcnt vmcnt(0)" ::: "memory");
    __builtin_amdgcn_sched_barrier(0);   // rule #18: keep uses below the wait

    short8 avh[8], avl[8];
#define UNPK(KS, qa, qb) \
    avh[KS] = (short8){(short)(qa.x & 0xffff),(short)(qa.y & 0xffff),(short)(qa.z & 0xffff),(short)(qa.w & 0xffff), \
                       (short)(qb.x & 0xffff),(short)(qb.y & 0xffff),(short)(qb.z & 0xffff),(short)(qb.w & 0xffff)}; \
    avl[KS] = (short8){(short)(qa.x >> 16),(short)(qa.y >> 16),(short)(qa.z >> 16),(short)(qa.w >> 16), \
                       (short)(qb.x >> 16),(short)(qb.y >> 16),(short)(qb.z >> 16),(short)(qb.w >> 16)};
    UNPK(0,q0,q1)  UNPK(1,q2,q3)  UNPK(2,q4,q5)  UNPK(3,q6,q7)
    UNPK(4,q8,q9)  UNPK(5,q10,q11) UNPK(6,q12,q13) UNPK(7,q14,q15)
#undef UNPK

    // ---- MFMA: 8 ksteps x 8 nfrags x (hi,lo) = 128 MFMA, 8-deep indep chains ----
    f32x4 acch[8] = {}, accl[8] = {};
#pragma unroll
    for (int ks = 0; ks < 8; ++ks)
#pragma unroll
      for (int nf = 0; nf < 8; ++nf) {
        short8 bv = *(const short8*)(pB + (size_t)nf * 16 * KK + ks * 32);
        acch[nf] = __builtin_amdgcn_mfma_f32_16x16x32_bf16(avh[ks], bv, acch[nf], 0, 0, 0);
        accl[nf] = __builtin_amdgcn_mfma_f32_16x16x32_bf16(avl[ks], bv, accl[nf], 0, 0, 0);
      }

    // ---- partial exchange: write [w][b][n ^ (kg<<4)] (2-way banks = free) ----
#pragma unroll
    for (int nf = 0; nf < 8; ++nf) {
      int cidx = (nf * 16 + lcol) ^ (kg << 4);
#pragma unroll
      for (int e = 0; e < 4; ++e)
        part[w * 2048 + (kg * 4 + e) * 128 + cidx] = acch[nf][e] + accl[nf][e];
    }
    __syncthreads();

    // ---- reduce 8 waves + diag + c, relu, pack, syscope store ----
    f32x4 s = {0.f, 0.f, 0.f, 0.f};
    int ridx = ob * 128 + (on ^ ((ob >> 2) << 4));
#pragma unroll
    for (int w2 = 0; w2 < 8; ++w2)
      s += *(const f32x4*)&part[w2 * 2048 + ridx];
    float z0 = fmaxf(s[0] + dv.x * zold0 + cv.x, 0.f);
    float z1 = fmaxf(s[1] + dv.y * zold1 + cv.y, 0.f);
    float z2 = fmaxf(s[2] + dv.z * zold2 + cv.z, 0.f);
    float z3 = fmaxf(s[3] + dv.w * zold3 + cv.w, 0.f);
    zold0 = z0; zold1 = z1; zold2 = z2; zold3 = z3;
    u32x4 zs = {packsplit(z0), packsplit(z1), packsplit(z2), packsplit(z3)};
    asm volatile("global_store_dwordx4 %0, %1, off sc0 sc1" :: "v"(pz), "v"(zs) : "memory");
    asm volatile("s_waitcnt vmcnt(0)" ::: "memory");   // stores at L3 before next round
    __syncthreads();                                   // also guards part[] reuse
  }

  // final write: out[n][b]
  out[(size_t)(n0 + on + 0) * NB + b0 + ob] = zold0;
  out[(size_t)(n0 + on + 1) * NB + b0 + ob] = zold1;
  out[(size_t)(n0 + on + 2) * NB + b0 + ob] = zold2;
  out[(size_t)(n0 + on + 3) * NB + b0 + ob] = zold3;
}

extern "C" void kernel_launch(void* const* d_in, const int* in_sizes, int n_in,
                              void* d_out, int out_size, void* d_ws, size_t ws_size,
                              hipStream_t stream) {
  const float* A    = (const float*)d_in[0];
  const float* S    = (const float*)d_in[1];
  const float* mraw = (const float*)d_in[2];
  const float* U    = (const float*)d_in[3];
  const float* bias = (const float*)d_in[4];
  const float* x    = (const float*)d_in[5];
  float* out = (float*)d_out;

  // non-aliasing workspace layout (<= 28MB + 8KB)
  char* base = (char*)d_ws;
  const size_t MB = 1024 * 1024;
  u16*   Aht   = (u16*)(base);             // [0,8MB)
  u16*   Alt   = (u16*)(base + 8 * MB);    // [8,16MB)
  u16*   Tobp  = (u16*)(base + 16 * MB);   // [16,24MB)
  float* cpp   = (float*)(base + 24 * MB); // [24,26MB)
  u32*   zpp   = (u32*)(base + 26 * MB);   // [26,28MB)
  float* Tdiag = (float*)(base + 28 * MB); // 8KB

  k_transpose_split<<<dim3(1024), dim3(256), 0, stream>>>(A, Aht, Alt);
  k_build_T<<<dim3(256), dim3(512), 0, stream>>>(Aht, Alt, S, mraw, Tobp, Tdiag);
  k_build_c<<<dim3(2048), dim3(256), 0, stream>>>(U, bias, x, cpp);
  (void)hipMemsetAsync(zpp, 0, (size_t)NB * NN * sizeof(u32), stream);  // z0 = 0

  void* kargs[] = { (void*)&Tobp, (void*)&Tdiag, (void*)&cpp, (void*)&zpp, (void*)&out };
  (void)hipLaunchCooperativeKernel((const void*)k_iterate, dim3(256), dim3(512),
                                   kargs, 0, stream);
}

// Round 6
// 2465.071 us; speedup vs baseline: 2.3021x; 1.3603x over previous
//
#include <hip/hip_runtime.h>
#include <hip/hip_bf16.h>

typedef unsigned short u16;
typedef unsigned int u32;
typedef __attribute__((ext_vector_type(8))) short short8;
typedef __attribute__((ext_vector_type(4))) float f32x4;
typedef __attribute__((ext_vector_type(4))) unsigned int u32x4;
typedef __attribute__((ext_vector_type(2))) unsigned int u32x2;

static constexpr int NB = 256;    // batch
static constexpr int NN = 2048;   // hidden n
static constexpr int KK = 2048;   // contraction dim
static constexpr int DD = 512;    // input features
static constexpr float ALPHA = 0.1f;
static constexpr int NITER = 128; // sync iters-to-tol ~79; margin for async staleness

__device__ __forceinline__ float bf2f(u16 u) {
  union { unsigned int i; float f; } v; v.i = ((unsigned int)u) << 16; return v.f;
}
__device__ __forceinline__ u16 f2bf(float f) {  // RNE bf16
  union { float f; unsigned int i; } v; v.f = f;
  unsigned int x = v.i;
  return (u16)((x + 0x7fffu + ((x >> 16) & 1u)) >> 16);
}

// ---------------- K1: Aht[i][k] = bf16(A[k][i]), Alt = residual ----------------
__global__ __launch_bounds__(256) void k_transpose_split(
    const float* __restrict__ A, u16* __restrict__ Aht, u16* __restrict__ Alt) {
  __shared__ float tile[64][65];
  int bx = blockIdx.x & 31;   // i-tile
  int by = blockIdx.x >> 5;   // k-tile
  int i0 = bx << 6, k0 = by << 6;
  int c = threadIdx.x & 63, r4 = threadIdx.x >> 6;
  for (int rr = r4; rr < 64; rr += 4)
    tile[rr][c] = A[(size_t)(k0 + rr) * NN + i0 + c];
  __syncthreads();
  for (int rr = r4; rr < 64; rr += 4) {
    float v = tile[c][rr];                       // = A[k0+c][i0+rr]
    size_t o = (size_t)(i0 + rr) * KK + k0 + c;  // Aht[i][k]
    u16 hv = f2bf(v);
    Aht[o] = hv;
    Alt[o] = f2bf(v - bf2f(hv));
  }
}

// --- K2: T = (1-a*m)I + a*(S - S^T - A^T A); off-diag -> bf16 Tob (diag zeroed),
//     exact fp32 diagonal -> Tdiag[n]. Split-bf16 3-MFMA for G = A^T A. ---
__global__ __launch_bounds__(512) void k_build_T(
    const u16* __restrict__ Aht, const u16* __restrict__ Alt,
    const float* __restrict__ S, const float* __restrict__ mraw,
    u16* __restrict__ Tob, float* __restrict__ Tdiag) {
  int bid = blockIdx.x;            // 256 blocks, output tile 128x128
  int it0 = (bid >> 4) << 7;
  int jt0 = (bid & 15) << 7;
  int lane = threadIdx.x & 63, wid = threadIdx.x >> 6;
  int wm = wid >> 2, wn = wid & 3; // 2x4 waves, wave tile 64x32
  int ib = it0 + wm * 64;
  int jb = jt0 + wn * 32;
  int lcol = lane & 15, kg = lane >> 4;
  f32x4 acc[4][2] = {};
  size_t ar[4], br[2];
#pragma unroll
  for (int mf = 0; mf < 4; ++mf) ar[mf] = (size_t)(ib + mf * 16 + lcol) * KK + kg * 8;
#pragma unroll
  for (int nf = 0; nf < 2; ++nf) br[nf] = (size_t)(jb + nf * 16 + lcol) * KK + kg * 8;
  for (int kk = 0; kk < KK; kk += 32) {
    short8 ah[4], al[4], bh[2], bl[2];
#pragma unroll
    for (int mf = 0; mf < 4; ++mf) {
      ah[mf] = *(const short8*)(Aht + ar[mf] + kk);
      al[mf] = *(const short8*)(Alt + ar[mf] + kk);
    }
#pragma unroll
    for (int nf = 0; nf < 2; ++nf) {
      bh[nf] = *(const short8*)(Aht + br[nf] + kk);
      bl[nf] = *(const short8*)(Alt + br[nf] + kk);
    }
#pragma unroll
    for (int mf = 0; mf < 4; ++mf)
#pragma unroll
      for (int nf = 0; nf < 2; ++nf) {
        acc[mf][nf] = __builtin_amdgcn_mfma_f32_16x16x32_bf16(ah[mf], bh[nf], acc[mf][nf], 0, 0, 0);
        acc[mf][nf] = __builtin_amdgcn_mfma_f32_16x16x32_bf16(al[mf], bh[nf], acc[mf][nf], 0, 0, 0);
        acc[mf][nf] = __builtin_amdgcn_mfma_f32_16x16x32_bf16(ah[mf], bl[nf], acc[mf][nf], 0, 0, 0);
      }
  }
  float m = log1pf(expf(mraw[0]));   // softplus
  float dg = 1.0f - ALPHA * m;
#pragma unroll
  for (int mf = 0; mf < 4; ++mf)
#pragma unroll
    for (int nf = 0; nf < 2; ++nf)
#pragma unroll
      for (int e = 0; e < 4; ++e) {
        int i = ib + mf * 16 + kg * 4 + e;   // D row = (lane>>4)*4+e  [m89-verified]
        int j = jb + nf * 16 + lcol;         // D col = lane&15
        float tv = ALPHA * (S[(size_t)i * NN + j] - S[(size_t)j * NN + i] - acc[mf][nf][e]);
        size_t o = (size_t)i * KK + j;
        if (i == j) {
          Tdiag[i] = tv + dg;   // exact fp32 diagonal
          Tob[o] = 0;
        } else {
          Tob[o] = f2bf(tv);
        }
      }
}

// ---------------- K3: cp[b][n] = a*(U[n,:]·x[b,:] + bias[n]) ----------------
__global__ __launch_bounds__(256) void k_build_c(
    const float* __restrict__ U, const float* __restrict__ bias,
    const float* __restrict__ x, float* __restrict__ cp) {
  int b = blockIdx.x >> 3;
  int n = ((blockIdx.x & 7) << 8) + threadIdx.x;
  const float4* xr = (const float4*)(x + (size_t)b * DD);
  const float4* ur = (const float4*)(U + (size_t)n * DD);
  float acc = 0.f;
  for (int d = 0; d < DD / 4; ++d) {
    float4 xv = xr[d], uv = ur[d];
    acc += xv.x * uv.x + xv.y * uv.y + xv.z * uv.z + xv.w * uv.w;
  }
  cp[(size_t)b * NN + n] = ALPHA * (acc + bias[n]);
}

// ---------------- K4: ASYNC fixed-point iteration (no barrier, no fences) ----------
// z = plain bf16 [b][n] (1 MB), accessed sc0 sc1 (L3-coherent). T_off bf16 cached
// (L2/L3); exact fp32 diagonal applied in registers (thread owns its outputs forever).
// Block = 16b x 128n; 8 waves split K (256 each); LDS exchange reduces the partials.
// A (z rows) prefetched cross-iteration: latency hides under exchange/reduce/store.
#define ALD(dst, OFF) \
  asm volatile("global_load_dwordx4 %0, %1, off offset:" OFF " sc0 sc1" \
               : "=v"(dst) : "v"(pa))
#define ALD_ALL \
  ALD(q0,"0");   ALD(q1,"64");  ALD(q2,"128"); ALD(q3,"192"); \
  ALD(q4,"256"); ALD(q5,"320"); ALD(q6,"384"); ALD(q7,"448");

__global__ __launch_bounds__(512) void k_iterate(
    const u16* __restrict__ Tob, const float* __restrict__ Tdiag,
    const float* __restrict__ cp, u16* zb, float* __restrict__ out) {
  int bid = blockIdx.x;
  int xcd = bid & 7, g = bid >> 3;
  int ntile = xcd * 2 + (g & 1);   // 0..15: XCD-local 1MB T_off slice (perf heuristic only)
  int btile = g >> 1;              // 0..15
  int b0 = btile * 16, n0 = ntile * 128;
  int tid = threadIdx.x, lane = tid & 63, w = tid >> 6;
  int lcol = lane & 15, kg = lane >> 4;
  int kbase = w * 256;             // this wave's K-slice

  const u16* pa = zb + (size_t)(b0 + lcol) * NN + kbase + kg * 8;       // A rows (z)
  const u16* pB = Tob + (size_t)(n0 + lcol) * KK + kbase + kg * 8;      // B rows (T_off)

  // epilogue ownership: thread owns (b0+ob, n0+on .. +3) FOREVER
  int ob = tid >> 5;           // 0..15
  int on = (tid & 31) * 4;     // 0..124
  const float4 cv = *(const float4*)(cp + (size_t)(b0 + ob) * NN + n0 + on);
  const float4 dv = *(const float4*)(Tdiag + n0 + on);
  u16* pz = zb + (size_t)(b0 + ob) * NN + n0 + on;
  float zold0 = 0.f, zold1 = 0.f, zold2 = 0.f, zold3 = 0.f;

  __shared__ float part[8 * 16 * 128];   // [wave][b][n^swz] 64 KiB

  u32x4 q0, q1, q2, q3, q4, q5, q6, q7;
  ALD_ALL;   // prologue prefetch; z is memset-0 so iter 0 computes relu(c) correctly

#pragma unroll 1
  for (int it = 0; it < NITER; ++it) {
    // ---- consume prefetched A ----
    asm volatile("s_waitcnt vmcnt(0)" ::: "memory");
    __builtin_amdgcn_sched_barrier(0);   // rule #18: keep uses below the wait
    short8 av[8];
    av[0] = __builtin_bit_cast(short8, q0);  av[1] = __builtin_bit_cast(short8, q1);
    av[2] = __builtin_bit_cast(short8, q2);  av[3] = __builtin_bit_cast(short8, q3);
    av[4] = __builtin_bit_cast(short8, q4);  av[5] = __builtin_bit_cast(short8, q5);
    av[6] = __builtin_bit_cast(short8, q6);  av[7] = __builtin_bit_cast(short8, q7);

    // ---- MFMA: 8 ksteps x 8 nfrags, B from L2-cached global ----
    f32x4 acc[8] = {};
#pragma unroll
    for (int ks = 0; ks < 8; ++ks)
#pragma unroll
      for (int nf = 0; nf < 8; ++nf) {
        short8 bv = *(const short8*)(pB + (size_t)nf * 16 * KK + ks * 32);
        acc[nf] = __builtin_amdgcn_mfma_f32_16x16x32_bf16(av[ks], bv, acc[nf], 0, 0, 0);
      }

    // ---- prefetch A for NEXT iteration (latency hides under exchange+reduce) ----
    ALD_ALL;

    // ---- partial exchange: write [w][b][n ^ (kg<<4)] (2-way banks = free) ----
#pragma unroll
    for (int nf = 0; nf < 8; ++nf) {
      int cidx = (nf * 16 + lcol) ^ (kg << 4);
#pragma unroll
      for (int e = 0; e < 4; ++e)
        part[w * 2048 + (kg * 4 + e) * 128 + cidx] = acc[nf][e];
    }
    __syncthreads();

    // ---- reduce 8 waves + diag + c, relu, pack bf16, coalesced 8B store ----
    f32x4 s = {0.f, 0.f, 0.f, 0.f};
    int ridx = ob * 128 + (on ^ ((ob >> 2) << 4));
#pragma unroll
    for (int w2 = 0; w2 < 8; ++w2)
      s += *(const f32x4*)&part[w2 * 2048 + ridx];
    float z0 = fmaxf(s[0] + dv.x * zold0 + cv.x, 0.f);
    float z1 = fmaxf(s[1] + dv.y * zold1 + cv.y, 0.f);
    float z2 = fmaxf(s[2] + dv.z * zold2 + cv.z, 0.f);
    float z3 = fmaxf(s[3] + dv.w * zold3 + cv.w, 0.f);
    zold0 = z0; zold1 = z1; zold2 = z2; zold3 = z3;
    u32x2 zs = {(u32)f2bf(z0) | ((u32)f2bf(z1) << 16),
                (u32)f2bf(z2) | ((u32)f2bf(z3) << 16)};
    asm volatile("global_store_dwordx2 %0, %1, off sc0 sc1" :: "v"(pz), "v"(zs) : "memory");
    __syncthreads();   // guards part[] reuse; store/prefetch drain at next loop-top wait
  }

  // final write: out[n][b]
  out[(size_t)(n0 + on + 0) * NB + b0 + ob] = zold0;
  out[(size_t)(n0 + on + 1) * NB + b0 + ob] = zold1;
  out[(size_t)(n0 + on + 2) * NB + b0 + ob] = zold2;
  out[(size_t)(n0 + on + 3) * NB + b0 + ob] = zold3;
}

extern "C" void kernel_launch(void* const* d_in, const int* in_sizes, int n_in,
                              void* d_out, int out_size, void* d_ws, size_t ws_size,
                              hipStream_t stream) {
  const float* A    = (const float*)d_in[0];
  const float* S    = (const float*)d_in[1];
  const float* mraw = (const float*)d_in[2];
  const float* U    = (const float*)d_in[3];
  const float* bias = (const float*)d_in[4];
  const float* x    = (const float*)d_in[5];
  float* out = (float*)d_out;

  // non-aliasing workspace layout
  char* base = (char*)d_ws;
  const size_t MB = 1024 * 1024;
  u16*   Aht   = (u16*)(base);             // [0,8MB)
  u16*   Alt   = (u16*)(base + 8 * MB);    // [8,16MB)
  u16*   Tobp  = (u16*)(base + 16 * MB);   // [16,24MB)
  float* cpp   = (float*)(base + 24 * MB); // [24,26MB)
  u16*   zbp   = (u16*)(base + 26 * MB);   // [26,27MB) plain bf16 z
  float* Tdiag = (float*)(base + 28 * MB); // 8KB

  k_transpose_split<<<dim3(1024), dim3(256), 0, stream>>>(A, Aht, Alt);
  k_build_T<<<dim3(256), dim3(512), 0, stream>>>(Aht, Alt, S, mraw, Tobp, Tdiag);
  k_build_c<<<dim3(2048), dim3(256), 0, stream>>>(U, bias, x, cpp);
  (void)hipMemsetAsync(zbp, 0, (size_t)NB * NN * sizeof(u16), stream);  // z0 = 0

  void* kargs[] = { (void*)&Tobp, (void*)&Tdiag, (void*)&cpp, (void*)&zbp, (void*)&out };
  (void)hipLaunchCooperativeKernel((const void*)k_iterate, dim3(256), dim3(512),
                                   kargs, 0, stream);
}

// Round 7
// 1859.575 us; speedup vs baseline: 3.0517x; 1.3256x over previous
//
#include <hip/hip_runtime.h>
#include <hip/hip_bf16.h>
#include <hip/hip_cooperative_groups.h>

namespace cg = cooperative_groups;

typedef unsigned short u16;
typedef unsigned int u32;
typedef __attribute__((ext_vector_type(8))) short short8;
typedef __attribute__((ext_vector_type(4))) float f32x4;
typedef __attribute__((ext_vector_type(4))) unsigned int u32x4;
typedef __attribute__((ext_vector_type(2))) unsigned int u32x2;

static constexpr int NB = 256;    // batch
static constexpr int NN = 2048;   // hidden n
static constexpr int KK = 2048;   // contraction dim
static constexpr int DD = 512;    // input features
static constexpr float ALPHA = 0.1f;
static constexpr int NITER = 128; // sync iters-to-tol ~79; margin for async staleness

__device__ __forceinline__ float bf2f(u16 u) {
  union { unsigned int i; float f; } v; v.i = ((unsigned int)u) << 16; return v.f;
}
__device__ __forceinline__ u16 f2bf(float f) {  // RNE bf16
  union { float f; unsigned int i; } v; v.f = f;
  unsigned int x = v.i;
  return (u16)((x + 0x7fffu + ((x >> 16) & 1u)) >> 16);
}

// ---------------- K1: Aht[i][k] = bf16(A[k][i]), Alt = residual ----------------
__global__ __launch_bounds__(256) void k_transpose_split(
    const float* __restrict__ A, u16* __restrict__ Aht, u16* __restrict__ Alt) {
  __shared__ float tile[64][65];
  int bx = blockIdx.x & 31;   // i-tile
  int by = blockIdx.x >> 5;   // k-tile
  int i0 = bx << 6, k0 = by << 6;
  int c = threadIdx.x & 63, r4 = threadIdx.x >> 6;
  for (int rr = r4; rr < 64; rr += 4)
    tile[rr][c] = A[(size_t)(k0 + rr) * NN + i0 + c];
  __syncthreads();
  for (int rr = r4; rr < 64; rr += 4) {
    float v = tile[c][rr];                       // = A[k0+c][i0+rr]
    size_t o = (size_t)(i0 + rr) * KK + k0 + c;  // Aht[i][k]
    u16 hv = f2bf(v);
    Aht[o] = hv;
    Alt[o] = f2bf(v - bf2f(hv));
  }
}

// --- K2: T = (1-a*m)I + a*(S - S^T - A^T A); off-diag -> bf16 Tob (diag zeroed),
//     exact fp32 diagonal -> Tdiag[n]. Split-bf16 3-MFMA for G = A^T A. ---
__global__ __launch_bounds__(512) void k_build_T(
    const u16* __restrict__ Aht, const u16* __restrict__ Alt,
    const float* __restrict__ S, const float* __restrict__ mraw,
    u16* __restrict__ Tob, float* __restrict__ Tdiag) {
  int bid = blockIdx.x;            // 256 blocks, output tile 128x128
  int it0 = (bid >> 4) << 7;
  int jt0 = (bid & 15) << 7;
  int lane = threadIdx.x & 63, wid = threadIdx.x >> 6;
  int wm = wid >> 2, wn = wid & 3; // 2x4 waves, wave tile 64x32
  int ib = it0 + wm * 64;
  int jb = jt0 + wn * 32;
  int lcol = lane & 15, kg = lane >> 4;
  f32x4 acc[4][2] = {};
  size_t ar[4], br[2];
#pragma unroll
  for (int mf = 0; mf < 4; ++mf) ar[mf] = (size_t)(ib + mf * 16 + lcol) * KK + kg * 8;
#pragma unroll
  for (int nf = 0; nf < 2; ++nf) br[nf] = (size_t)(jb + nf * 16 + lcol) * KK + kg * 8;
  for (int kk = 0; kk < KK; kk += 32) {
    short8 ah[4], al[4], bh[2], bl[2];
#pragma unroll
    for (int mf = 0; mf < 4; ++mf) {
      ah[mf] = *(const short8*)(Aht + ar[mf] + kk);
      al[mf] = *(const short8*)(Alt + ar[mf] + kk);
    }
#pragma unroll
    for (int nf = 0; nf < 2; ++nf) {
      bh[nf] = *(const short8*)(Aht + br[nf] + kk);
      bl[nf] = *(const short8*)(Alt + br[nf] + kk);
    }
#pragma unroll
    for (int mf = 0; mf < 4; ++mf)
#pragma unroll
      for (int nf = 0; nf < 2; ++nf) {
        acc[mf][nf] = __builtin_amdgcn_mfma_f32_16x16x32_bf16(ah[mf], bh[nf], acc[mf][nf], 0, 0, 0);
        acc[mf][nf] = __builtin_amdgcn_mfma_f32_16x16x32_bf16(al[mf], bh[nf], acc[mf][nf], 0, 0, 0);
        acc[mf][nf] = __builtin_amdgcn_mfma_f32_16x16x32_bf16(ah[mf], bl[nf], acc[mf][nf], 0, 0, 0);
      }
  }
  float m = log1pf(expf(mraw[0]));   // softplus
  float dg = 1.0f - ALPHA * m;
#pragma unroll
  for (int mf = 0; mf < 4; ++mf)
#pragma unroll
    for (int nf = 0; nf < 2; ++nf)
#pragma unroll
      for (int e = 0; e < 4; ++e) {
        int i = ib + mf * 16 + kg * 4 + e;   // D row = (lane>>4)*4+e  [m89-verified]
        int j = jb + nf * 16 + lcol;         // D col = lane&15
        float tv = ALPHA * (S[(size_t)i * NN + j] - S[(size_t)j * NN + i] - acc[mf][nf][e]);
        size_t o = (size_t)i * KK + j;
        if (i == j) {
          Tdiag[i] = tv + dg;   // exact fp32 diagonal
          Tob[o] = 0;
        } else {
          Tob[o] = f2bf(tv);
        }
      }
}

// ---------------- K3: cp[b][n] = a*(U[n,:]·x[b,:] + bias[n]) ----------------
__global__ __launch_bounds__(256) void k_build_c(
    const float* __restrict__ U, const float* __restrict__ bias,
    const float* __restrict__ x, float* __restrict__ cp) {
  int b = blockIdx.x >> 3;
  int n = ((blockIdx.x & 7) << 8) + threadIdx.x;
  const float4* xr = (const float4*)(x + (size_t)b * DD);
  const float4* ur = (const float4*)(U + (size_t)n * DD);
  float acc = 0.f;
  for (int d = 0; d < DD / 4; ++d) {
    float4 xv = xr[d], uv = ur[d];
    acc += xv.x * uv.x + xv.y * uv.y + xv.z * uv.z + xv.w * uv.w;
  }
  cp[(size_t)b * NN + n] = ALPHA * (acc + bias[n]);
}

// ---------------- K4: ASYNC fixed-point iteration, fully counted waits ----------
// Tile = 32b x 64n; 8 waves split K (256 each); LDS exchange; tile->XCD assignment
// from the REAL XCC_ID (bijective rank, correct under any dispatch). Raw barriers
// (lgkmcnt only, NO vmcnt drain); z-store never waited; B triple-buffered vmcnt(8).
#define ALD(dst, base, OFF) \
  asm volatile("global_load_dwordx4 %0, %1, off offset:" OFF " sc0 sc1" \
               : "=v"(dst) : "v"(base))
#define BLD(dst, base, OFF) \
  asm volatile("global_load_dwordx4 %0, %1, off offset:" OFF \
               : "=v"(dst) : "v"(base))
#define BLDS(S, OFF) \
  BLD(bb[S][0], pb0, OFF); BLD(bb[S][1], pb1, OFF); \
  BLD(bb[S][2], pb2, OFF); BLD(bb[S][3], pb3, OFF);
#define VWAIT(NSTR) \
  asm volatile("s_waitcnt vmcnt(" NSTR ")" ::: "memory"); \
  __builtin_amdgcn_sched_barrier(0)
#define BARRIER \
  asm volatile("s_waitcnt lgkmcnt(0)\n\ts_barrier" ::: "memory")
#define PREF_A \
  ALD(qa[0], pa0, "0");   ALD(qa[1], pa0, "64");  ALD(qa[2], pa0, "128"); ALD(qa[3], pa0, "192"); \
  ALD(qa[4], pa0, "256"); ALD(qa[5], pa0, "320"); ALD(qa[6], pa0, "384"); ALD(qa[7], pa0, "448"); \
  ALD(qa[8], pa1, "0");   ALD(qa[9], pa1, "64");  ALD(qa[10], pa1, "128"); ALD(qa[11], pa1, "192"); \
  ALD(qa[12], pa1, "256"); ALD(qa[13], pa1, "320"); ALD(qa[14], pa1, "384"); ALD(qa[15], pa1, "448");
#define MMS(KS, S) do { \
  short8 a0_ = __builtin_bit_cast(short8, qa[KS]); \
  short8 a1_ = __builtin_bit_cast(short8, qa[8 + (KS)]); \
  short8 b0_ = __builtin_bit_cast(short8, bb[S][0]); \
  short8 b1_ = __builtin_bit_cast(short8, bb[S][1]); \
  short8 b2_ = __builtin_bit_cast(short8, bb[S][2]); \
  short8 b3_ = __builtin_bit_cast(short8, bb[S][3]); \
  acc[0][0] = __builtin_amdgcn_mfma_f32_16x16x32_bf16(a0_, b0_, acc[0][0], 0, 0, 0); \
  acc[1][0] = __builtin_amdgcn_mfma_f32_16x16x32_bf16(a1_, b0_, acc[1][0], 0, 0, 0); \
  acc[0][1] = __builtin_amdgcn_mfma_f32_16x16x32_bf16(a0_, b1_, acc[0][1], 0, 0, 0); \
  acc[1][1] = __builtin_amdgcn_mfma_f32_16x16x32_bf16(a1_, b1_, acc[1][1], 0, 0, 0); \
  acc[0][2] = __builtin_amdgcn_mfma_f32_16x16x32_bf16(a0_, b2_, acc[0][2], 0, 0, 0); \
  acc[1][2] = __builtin_amdgcn_mfma_f32_16x16x32_bf16(a1_, b2_, acc[1][2], 0, 0, 0); \
  acc[0][3] = __builtin_amdgcn_mfma_f32_16x16x32_bf16(a0_, b3_, acc[0][3], 0, 0, 0); \
  acc[1][3] = __builtin_amdgcn_mfma_f32_16x16x32_bf16(a1_, b3_, acc[1][3], 0, 0, 0); \
} while (0)

__global__ __launch_bounds__(512, 2) void k_iterate(
    const u16* __restrict__ Tob, const float* __restrict__ Tdiag,
    const float* __restrict__ cp, u16* zb, u32* xcds, float* __restrict__ out) {
  int bid = blockIdx.x;
  int tid = threadIdx.x, lane = tid & 63, w = tid >> 6;

  __shared__ float part[16384];   // 64 KiB: [wave][32b][64n^swz]; xl aliases it early

  // ---- phase 0: measured-XCD tile assignment (bijective rank; locality-only) ----
  u32 xreg;
  asm volatile("s_getreg_b32 %0, hwreg(HW_REG_XCC_ID)" : "=s"(xreg));
  u32 myxcd = xreg & 7u;
  if (tid == 0) {
    __hip_atomic_store(xcds + bid, myxcd, __ATOMIC_RELAXED, __HIP_MEMORY_SCOPE_SYSTEM);
    asm volatile("s_waitcnt vmcnt(0)" ::: "memory");
  }
  cg::this_grid().sync();
  u32* xl = (u32*)part;
  if (tid < 64) {
#pragma unroll
    for (int j = 0; j < 4; ++j)
      xl[tid + j * 64] = __hip_atomic_load(xcds + tid + j * 64,
                                           __ATOMIC_RELAXED, __HIP_MEMORY_SCOPE_SYSTEM);
  }
  __syncthreads();
  int rank = 0;
  for (int b = 0; b < 256; ++b) {
    u32 xb = xl[b] & 7u;
    rank += (xb < myxcd) || (xb == myxcd && b < bid);
  }
  __syncthreads();   // xl dead; part[] free for exchange

  int ntile = rank >> 3;    // 0..31 (8 consecutive ranks share ntile -> same XCD)
  int btile = rank & 7;     // 0..7
  int b0 = btile * 32, n0 = ntile * 64;

  // ---- per-lane geometry ----
  int lcol = lane & 15, kg = lane >> 4;
  int kbase = w * 256;
  const u16* pa0 = zb + (size_t)(b0 + lcol) * NN + kbase + kg * 8;
  const u16* pa1 = pa0 + (size_t)16 * NN;
  const u16* pbb = Tob + (size_t)(n0 + lcol) * KK + kbase + kg * 8;
  const u16* pb0 = pbb;
  const u16* pb1 = pbb + (size_t)16 * KK;
  const u16* pb2 = pbb + (size_t)32 * KK;
  const u16* pb3 = pbb + (size_t)48 * KK;

  int ob = tid >> 4;            // 0..31
  int on = (tid & 15) << 2;     // 0..60
  const float4 cv = *(const float4*)(cp + (size_t)(b0 + ob) * NN + n0 + on);
  const float4 dv = *(const float4*)(Tdiag + n0 + on);
  u16* pz = zb + (size_t)(b0 + ob) * NN + n0 + on;
  int kgr = (ob >> 2) & 3;
  int ridx = ob * 64 + (on ^ (kgr << 4));
  float zold0 = 0.f, zold1 = 0.f, zold2 = 0.f, zold3 = 0.f;

  u32x4 qa[16];
  u32x4 bb[3][4];

  // prologue: A prefetch + dummy store (keeps loop-top vmcnt(1) invariant)
  PREF_A;
  {
    u32x2 z0v = {0u, 0u};
    asm volatile("global_store_dwordx2 %0, %1, off sc0 sc1" :: "v"(pz), "v"(z0v) : "memory");
  }

#pragma unroll 1
  for (int it = 0; it < NITER; ++it) {
    VWAIT("1");                      // A(16) done; z-store may still be in flight
    f32x4 acc[2][4] = {};

    // B triple-buffered pipeline; stage ks waits its buffer with counted vmcnt
    BLDS(0, "0") BLDS(1, "64")
    BLDS(2, "128") VWAIT("8"); MMS(0, 0);
    BLDS(0, "192") VWAIT("8"); MMS(1, 1);
    BLDS(1, "256") VWAIT("8"); MMS(2, 2);
    BLDS(2, "320") VWAIT("8"); MMS(3, 0);
    BLDS(0, "384") VWAIT("8"); MMS(4, 1);
    BLDS(1, "448") VWAIT("8"); MMS(5, 2);
    VWAIT("4"); MMS(6, 0);
    VWAIT("0"); MMS(7, 1);

    PREF_A;   // next iteration's A: latency hides under exchange/reduce/store

    // ---- partial exchange (swizzled; 2-way banks = free) ----
#pragma unroll
    for (int af = 0; af < 2; ++af)
#pragma unroll
      for (int bf = 0; bf < 4; ++bf) {
        int cs = ((bf ^ kg) & 3) * 16 + lcol;
        int bb_ = af * 16 + kg * 4;
#pragma unroll
        for (int e = 0; e < 4; ++e)
          part[w * 2048 + (bb_ + e) * 64 + cs] = acc[af][bf][e];
      }
    BARRIER;   // lgkmcnt(0) + s_barrier: NO vmcnt drain (A/store stay in flight)

    // ---- reduce 8 waves + diag + c, relu, pack, 8B sc store ----
    f32x4 s = {0.f, 0.f, 0.f, 0.f};
#pragma unroll
    for (int w2 = 0; w2 < 8; ++w2)
      s += *(const f32x4*)&part[w2 * 2048 + ridx];
    float z0 = fmaxf(s[0] + dv.x * zold0 + cv.x, 0.f);
    float z1 = fmaxf(s[1] + dv.y * zold1 + cv.y, 0.f);
    float z2 = fmaxf(s[2] + dv.z * zold2 + cv.z, 0.f);
    float z3 = fmaxf(s[3] + dv.w * zold3 + cv.w, 0.f);
    zold0 = z0; zold1 = z1; zold2 = z2; zold3 = z3;
    u32x2 zs = {(u32)f2bf(z0) | ((u32)f2bf(z1) << 16),
                (u32)f2bf(z2) | ((u32)f2bf(z3) << 16)};
    asm volatile("global_store_dwordx2 %0, %1, off sc0 sc1" :: "v"(pz), "v"(zs) : "memory");
    BARRIER;   // part[] reuse guard; store ack never waited
  }

  // final write: out[n][b]
  out[(size_t)(n0 + on + 0) * NB + b0 + ob] = zold0;
  out[(size_t)(n0 + on + 1) * NB + b0 + ob] = zold1;
  out[(size_t)(n0 + on + 2) * NB + b0 + ob] = zold2;
  out[(size_t)(n0 + on + 3) * NB + b0 + ob] = zold3;
}

extern "C" void kernel_launch(void* const* d_in, const int* in_sizes, int n_in,
                              void* d_out, int out_size, void* d_ws, size_t ws_size,
                              hipStream_t stream) {
  const float* A    = (const float*)d_in[0];
  const float* S    = (const float*)d_in[1];
  const float* mraw = (const float*)d_in[2];
  const float* U    = (const float*)d_in[3];
  const float* bias = (const float*)d_in[4];
  const float* x    = (const float*)d_in[5];
  float* out = (float*)d_out;

  char* base = (char*)d_ws;
  const size_t MB = 1024 * 1024;
  u16*   Aht   = (u16*)(base);                       // [0,8MB)
  u16*   Alt   = (u16*)(base + 8 * MB);              // [8,16MB)
  u16*   Tobp  = (u16*)(base + 16 * MB);             // [16,24MB)
  float* cpp   = (float*)(base + 24 * MB);           // [24,26MB)
  u16*   zbp   = (u16*)(base + 26 * MB);             // [26,27MB) bf16 z
  float* Tdiag = (float*)(base + 28 * MB);           // 8KB
  u32*   xcds  = (u32*)(base + 28 * MB + 16384);     // 1KB

  k_transpose_split<<<dim3(1024), dim3(256), 0, stream>>>(A, Aht, Alt);
  k_build_T<<<dim3(256), dim3(512), 0, stream>>>(Aht, Alt, S, mraw, Tobp, Tdiag);
  k_build_c<<<dim3(2048), dim3(256), 0, stream>>>(U, bias, x, cpp);
  (void)hipMemsetAsync(zbp, 0, (size_t)NB * NN * sizeof(u16), stream);  // z0 = 0

  void* kargs[] = { (void*)&Tobp, (void*)&Tdiag, (void*)&cpp,
                    (void*)&zbp, (void*)&xcds, (void*)&out };
  (void)hipLaunchCooperativeKernel((const void*)k_iterate, dim3(256), dim3(512),
                                   kargs, 0, stream);
}

// Round 8
// 1058.961 us; speedup vs baseline: 5.3589x; 1.7560x over previous
//
#include <hip/hip_runtime.h>
#include <hip/hip_bf16.h>
#include <hip/hip_cooperative_groups.h>

namespace cg = cooperative_groups;

typedef unsigned short u16;
typedef unsigned int u32;
typedef __attribute__((ext_vector_type(8))) short short8;
typedef __attribute__((ext_vector_type(4))) float f32x4;
typedef __attribute__((ext_vector_type(4))) unsigned int u32x4;
typedef __attribute__((ext_vector_type(2))) unsigned int u32x2;

static constexpr int NB = 256;    // batch
static constexpr int NN = 2048;   // hidden n
static constexpr int KK = 2048;   // contraction dim
static constexpr int DD = 512;    // input features
static constexpr float ALPHA = 0.1f;
static constexpr int NITER = 128; // sync iters-to-tol ~79; margin for async staleness

__device__ __forceinline__ float bf2f(u16 u) {
  union { unsigned int i; float f; } v; v.i = ((unsigned int)u) << 16; return v.f;
}
__device__ __forceinline__ u16 f2bf(float f) {  // RNE bf16
  union { float f; unsigned int i; } v; v.f = f;
  unsigned int x = v.i;
  return (u16)((x + 0x7fffu + ((x >> 16) & 1u)) >> 16);
}

// ---------------- K1: Aht[i][k] = bf16(A[k][i]), Alt = residual ----------------
__global__ __launch_bounds__(256) void k_transpose_split(
    const float* __restrict__ A, u16* __restrict__ Aht, u16* __restrict__ Alt) {
  __shared__ float tile[64][65];
  int bx = blockIdx.x & 31;   // i-tile
  int by = blockIdx.x >> 5;   // k-tile
  int i0 = bx << 6, k0 = by << 6;
  int c = threadIdx.x & 63, r4 = threadIdx.x >> 6;
  for (int rr = r4; rr < 64; rr += 4)
    tile[rr][c] = A[(size_t)(k0 + rr) * NN + i0 + c];
  __syncthreads();
  for (int rr = r4; rr < 64; rr += 4) {
    float v = tile[c][rr];                       // = A[k0+c][i0+rr]
    size_t o = (size_t)(i0 + rr) * KK + k0 + c;  // Aht[i][k]
    u16 hv = f2bf(v);
    Aht[o] = hv;
    Alt[o] = f2bf(v - bf2f(hv));
  }
}

// --- K2: T = (1-a*m)I + a*(S - S^T - A^T A); off-diag -> bf16 Tob (diag zeroed),
//     exact fp32 diagonal -> Tdiag[n]. Split-bf16 3-MFMA for G = A^T A. ---
__global__ __launch_bounds__(512) void k_build_T(
    const u16* __restrict__ Aht, const u16* __restrict__ Alt,
    const float* __restrict__ S, const float* __restrict__ mraw,
    u16* __restrict__ Tob, float* __restrict__ Tdiag) {
  int bid = blockIdx.x;            // 256 blocks, output tile 128x128
  int it0 = (bid >> 4) << 7;
  int jt0 = (bid & 15) << 7;
  int lane = threadIdx.x & 63, wid = threadIdx.x >> 6;
  int wm = wid >> 2, wn = wid & 3; // 2x4 waves, wave tile 64x32
  int ib = it0 + wm * 64;
  int jb = jt0 + wn * 32;
  int lcol = lane & 15, kg = lane >> 4;
  f32x4 acc[4][2] = {};
  size_t ar[4], br[2];
#pragma unroll
  for (int mf = 0; mf < 4; ++mf) ar[mf] = (size_t)(ib + mf * 16 + lcol) * KK + kg * 8;
#pragma unroll
  for (int nf = 0; nf < 2; ++nf) br[nf] = (size_t)(jb + nf * 16 + lcol) * KK + kg * 8;
  for (int kk = 0; kk < KK; kk += 32) {
    short8 ah[4], al[4], bh[2], bl[2];
#pragma unroll
    for (int mf = 0; mf < 4; ++mf) {
      ah[mf] = *(const short8*)(Aht + ar[mf] + kk);
      al[mf] = *(const short8*)(Alt + ar[mf] + kk);
    }
#pragma unroll
    for (int nf = 0; nf < 2; ++nf) {
      bh[nf] = *(const short8*)(Aht + br[nf] + kk);
      bl[nf] = *(const short8*)(Alt + br[nf] + kk);
    }
#pragma unroll
    for (int mf = 0; mf < 4; ++mf)
#pragma unroll
      for (int nf = 0; nf < 2; ++nf) {
        acc[mf][nf] = __builtin_amdgcn_mfma_f32_16x16x32_bf16(ah[mf], bh[nf], acc[mf][nf], 0, 0, 0);
        acc[mf][nf] = __builtin_amdgcn_mfma_f32_16x16x32_bf16(al[mf], bh[nf], acc[mf][nf], 0, 0, 0);
        acc[mf][nf] = __builtin_amdgcn_mfma_f32_16x16x32_bf16(ah[mf], bl[nf], acc[mf][nf], 0, 0, 0);
      }
  }
  float m = log1pf(expf(mraw[0]));   // softplus
  float dg = 1.0f - ALPHA * m;
#pragma unroll
  for (int mf = 0; mf < 4; ++mf)
#pragma unroll
    for (int nf = 0; nf < 2; ++nf)
#pragma unroll
      for (int e = 0; e < 4; ++e) {
        int i = ib + mf * 16 + kg * 4 + e;   // D row = (lane>>4)*4+e  [m89-verified]
        int j = jb + nf * 16 + lcol;         // D col = lane&15
        float tv = ALPHA * (S[(size_t)i * NN + j] - S[(size_t)j * NN + i] - acc[mf][nf][e]);
        size_t o = (size_t)i * KK + j;
        if (i == j) {
          Tdiag[i] = tv + dg;   // exact fp32 diagonal
          Tob[o] = 0;
        } else {
          Tob[o] = f2bf(tv);
        }
      }
}

// ---------------- K3: cp[b][n] = a*(U[n,:]·x[b,:] + bias[n]) ----------------
__global__ __launch_bounds__(256) void k_build_c(
    const float* __restrict__ U, const float* __restrict__ bias,
    const float* __restrict__ x, float* __restrict__ cp) {
  int b = blockIdx.x >> 3;
  int n = ((blockIdx.x & 7) << 8) + threadIdx.x;
  const float4* xr = (const float4*)(x + (size_t)b * DD);
  const float4* ur = (const float4*)(U + (size_t)n * DD);
  float acc = 0.f;
  for (int d = 0; d < DD / 4; ++d) {
    float4 xv = xr[d], uv = ur[d];
    acc += xv.x * uv.x + xv.y * uv.y + xv.z * uv.z + xv.w * uv.w;
  }
  cp[(size_t)b * NN + n] = ALPHA * (acc + bias[n]);
}

// ---------------- K4: ASYNC fixed-point iteration, B-IN-REGISTERS ----------
// T never changes: each wave holds its entire B-slice (64n x 256k bf16 = 128 VGPR)
// in registers for all 128 iterations. Per-iter VMEM = A z-reads (sc0 sc1, L3)
// prefetched cross-iteration + one 8B z-store (never waited). Raw barriers
// (lgkmcnt only). Tile->XCD grouping from measured XCC_ID (bijective rank).
#define ALD(dst, base, OFF) \
  asm volatile("global_load_dwordx4 %0, %1, off offset:" OFF " sc0 sc1" \
               : "=v"(dst) : "v"(base))
#define VWAIT(NSTR) \
  asm volatile("s_waitcnt vmcnt(" NSTR ")" ::: "memory"); \
  __builtin_amdgcn_sched_barrier(0)
#define BARRIER \
  asm volatile("s_waitcnt lgkmcnt(0)\n\ts_barrier" ::: "memory")
#define PREF_A \
  ALD(qa[0], pa0, "0");   ALD(qa[1], pa0, "64");  ALD(qa[2], pa0, "128"); ALD(qa[3], pa0, "192"); \
  ALD(qa[4], pa0, "256"); ALD(qa[5], pa0, "320"); ALD(qa[6], pa0, "384"); ALD(qa[7], pa0, "448"); \
  ALD(qa[8], pa1, "0");   ALD(qa[9], pa1, "64");  ALD(qa[10], pa1, "128"); ALD(qa[11], pa1, "192"); \
  ALD(qa[12], pa1, "256"); ALD(qa[13], pa1, "320"); ALD(qa[14], pa1, "384"); ALD(qa[15], pa1, "448");
#define MMS(KS) do { \
  short8 a0_ = __builtin_bit_cast(short8, qa[KS]); \
  short8 a1_ = __builtin_bit_cast(short8, qa[8 + (KS)]); \
  acc[0][0] = __builtin_amdgcn_mfma_f32_16x16x32_bf16(a0_, breg[0][KS], acc[0][0], 0, 0, 0); \
  acc[1][0] = __builtin_amdgcn_mfma_f32_16x16x32_bf16(a1_, breg[0][KS], acc[1][0], 0, 0, 0); \
  acc[0][1] = __builtin_amdgcn_mfma_f32_16x16x32_bf16(a0_, breg[1][KS], acc[0][1], 0, 0, 0); \
  acc[1][1] = __builtin_amdgcn_mfma_f32_16x16x32_bf16(a1_, breg[1][KS], acc[1][1], 0, 0, 0); \
  acc[0][2] = __builtin_amdgcn_mfma_f32_16x16x32_bf16(a0_, breg[2][KS], acc[0][2], 0, 0, 0); \
  acc[1][2] = __builtin_amdgcn_mfma_f32_16x16x32_bf16(a1_, breg[2][KS], acc[1][2], 0, 0, 0); \
  acc[0][3] = __builtin_amdgcn_mfma_f32_16x16x32_bf16(a0_, breg[3][KS], acc[0][3], 0, 0, 0); \
  acc[1][3] = __builtin_amdgcn_mfma_f32_16x16x32_bf16(a1_, breg[3][KS], acc[1][3], 0, 0, 0); \
} while (0)

__global__ __launch_bounds__(512, 2) void k_iterate(
    const u16* __restrict__ Tob, const float* __restrict__ Tdiag,
    const float* __restrict__ cp, u16* zb, u32* xcds, float* __restrict__ out) {
  int bid = blockIdx.x;
  int tid = threadIdx.x, lane = tid & 63, w = tid >> 6;

  __shared__ float part[16384];   // 64 KiB: [wave][32b][64n^swz]; xl aliases it early

  // ---- phase 0: measured-XCD tile assignment (bijective rank; locality-only) ----
  u32 xreg;
  asm volatile("s_getreg_b32 %0, hwreg(HW_REG_XCC_ID)" : "=s"(xreg));
  u32 myxcd = xreg & 7u;
  if (tid == 0) {
    __hip_atomic_store(xcds + bid, myxcd, __ATOMIC_RELAXED, __HIP_MEMORY_SCOPE_SYSTEM);
    asm volatile("s_waitcnt vmcnt(0)" ::: "memory");
  }
  cg::this_grid().sync();
  u32* xl = (u32*)part;
  if (tid < 64) {
#pragma unroll
    for (int j = 0; j < 4; ++j)
      xl[tid + j * 64] = __hip_atomic_load(xcds + tid + j * 64,
                                           __ATOMIC_RELAXED, __HIP_MEMORY_SCOPE_SYSTEM);
  }
  __syncthreads();
  int rank = 0;
  for (int b = 0; b < 256; ++b) {
    u32 xb = xl[b] & 7u;
    rank += (xb < myxcd) || (xb == myxcd && b < bid);
  }
  __syncthreads();   // xl dead; part[] free for exchange

  int ntile = rank >> 3;    // 0..31 (8 consecutive ranks share ntile -> same XCD)
  int btile = rank & 7;     // 0..7
  int b0 = btile * 32, n0 = ntile * 64;

  // ---- per-lane geometry ----
  int lcol = lane & 15, kg = lane >> 4;
  int kbase = w * 256;
  const u16* pa0 = zb + (size_t)(b0 + lcol) * NN + kbase + kg * 8;
  const u16* pa1 = pa0 + (size_t)16 * NN;
  const u16* pbb = Tob + (size_t)(n0 + lcol) * KK + kbase + kg * 8;

  // ---- B-slice -> registers, once (plain cached loads; T is read-only) ----
  short8 breg[4][8];   // [nfrag][kstep] = 32 frags x 4 VGPR = 128 VGPRs
#pragma unroll
  for (int nf = 0; nf < 4; ++nf)
#pragma unroll
    for (int ks = 0; ks < 8; ++ks)
      breg[nf][ks] = *(const short8*)(pbb + (size_t)nf * 16 * KK + ks * 32);

  int ob = tid >> 4;            // 0..31
  int on = (tid & 15) << 2;     // 0..60
  const float4 cv = *(const float4*)(cp + (size_t)(b0 + ob) * NN + n0 + on);
  const float4 dv = *(const float4*)(Tdiag + n0 + on);
  u16* pz = zb + (size_t)(b0 + ob) * NN + n0 + on;
  int kgr = (ob >> 2) & 3;
  int ridx = ob * 64 + (on ^ (kgr << 4));
  float zold0 = 0.f, zold1 = 0.f, zold2 = 0.f, zold3 = 0.f;

  u32x4 qa[16];

  // prologue: A prefetch + dummy store (keeps loop-top vmcnt(1) invariant)
  PREF_A;
  {
    u32x2 z0v = {0u, 0u};
    asm volatile("global_store_dwordx2 %0, %1, off sc0 sc1" :: "v"(pz), "v"(z0v) : "memory");
  }

#pragma unroll 1
  for (int it = 0; it < NITER; ++it) {
    VWAIT("1");                      // A(16) done; z-store may still be in flight
    f32x4 acc[2][4] = {};
    MMS(0); MMS(1); MMS(2); MMS(3); MMS(4); MMS(5); MMS(6); MMS(7);

    PREF_A;   // next iteration's A: latency hides under exchange/reduce/store

    // ---- partial exchange (swizzled; 2-way banks = free) ----
#pragma unroll
    for (int af = 0; af < 2; ++af)
#pragma unroll
      for (int bf = 0; bf < 4; ++bf) {
        int cs = ((bf ^ kg) & 3) * 16 + lcol;
        int bb_ = af * 16 + kg * 4;
#pragma unroll
        for (int e = 0; e < 4; ++e)
          part[w * 2048 + (bb_ + e) * 64 + cs] = acc[af][bf][e];
      }
    BARRIER;   // lgkmcnt(0) + s_barrier: NO vmcnt drain (A/store stay in flight)

    // ---- reduce 8 waves + diag + c, relu, pack, 8B sc store ----
    f32x4 s = {0.f, 0.f, 0.f, 0.f};
#pragma unroll
    for (int w2 = 0; w2 < 8; ++w2)
      s += *(const f32x4*)&part[w2 * 2048 + ridx];
    float z0 = fmaxf(s[0] + dv.x * zold0 + cv.x, 0.f);
    float z1 = fmaxf(s[1] + dv.y * zold1 + cv.y, 0.f);
    float z2 = fmaxf(s[2] + dv.z * zold2 + cv.z, 0.f);
    float z3 = fmaxf(s[3] + dv.w * zold3 + cv.w, 0.f);
    zold0 = z0; zold1 = z1; zold2 = z2; zold3 = z3;
    u32x2 zs = {(u32)f2bf(z0) | ((u32)f2bf(z1) << 16),
                (u32)f2bf(z2) | ((u32)f2bf(z3) << 16)};
    asm volatile("global_store_dwordx2 %0, %1, off sc0 sc1" :: "v"(pz), "v"(zs) : "memory");
    BARRIER;   // part[] reuse guard; store ack never waited
  }

  // final write: out[n][b]
  out[(size_t)(n0 + on + 0) * NB + b0 + ob] = zold0;
  out[(size_t)(n0 + on + 1) * NB + b0 + ob] = zold1;
  out[(size_t)(n0 + on + 2) * NB + b0 + ob] = zold2;
  out[(size_t)(n0 + on + 3) * NB + b0 + ob] = zold3;
}

extern "C" void kernel_launch(void* const* d_in, const int* in_sizes, int n_in,
                              void* d_out, int out_size, void* d_ws, size_t ws_size,
                              hipStream_t stream) {
  const float* A    = (const float*)d_in[0];
  const float* S    = (const float*)d_in[1];
  const float* mraw = (const float*)d_in[2];
  const float* U    = (const float*)d_in[3];
  const float* bias = (const float*)d_in[4];
  const float* x    = (const float*)d_in[5];
  float* out = (float*)d_out;

  char* base = (char*)d_ws;
  const size_t MB = 1024 * 1024;
  u16*   Aht   = (u16*)(base);                       // [0,8MB)
  u16*   Alt   = (u16*)(base + 8 * MB);              // [8,16MB)
  u16*   Tobp  = (u16*)(base + 16 * MB);             // [16,24MB)
  float* cpp   = (float*)(base + 24 * MB);           // [24,26MB)
  u16*   zbp   = (u16*)(base + 26 * MB);             // [26,27MB) bf16 z
  float* Tdiag = (float*)(base + 28 * MB);           // 8KB
  u32*   xcds  = (u32*)(base + 28 * MB + 16384);     // 1KB

  k_transpose_split<<<dim3(1024), dim3(256), 0, stream>>>(A, Aht, Alt);
  k_build_T<<<dim3(256), dim3(512), 0, stream>>>(Aht, Alt, S, mraw, Tobp, Tdiag);
  k_build_c<<<dim3(2048), dim3(256), 0, stream>>>(U, bias, x, cpp);
  (void)hipMemsetAsync(zbp, 0, (size_t)NB * NN * sizeof(u16), stream);  // z0 = 0

  void* kargs[] = { (void*)&Tobp, (void*)&Tdiag, (void*)&cpp,
                    (void*)&zbp, (void*)&xcds, (void*)&out };
  (void)hipLaunchCooperativeKernel((const void*)k_iterate, dim3(256), dim3(512),
                                   kargs, 0, stream);
}